// Round 6
// baseline (163.579 us; speedup 1.0000x reference)
//
#include <hip/hip_runtime.h>
#include <math.h>

#define BLOCK 256
#define NN 100
#define GB 4          // boxes per pass-B block
#define NGRP (NN / GB) // 25 box-groups per batch image

__device__ __forceinline__ float fast_rcp(float x) { return __builtin_amdgcn_rcpf(x); }

// ---------------------------------------------------------------------------
// Fused match kernel.
//  blocks [0, NBB)          : pass B — per-box column max over all anchors.
//  blocks [NBB, NBB + B*NA) : pass A — per-anchor row max over 100 boxes.
// Pass-B blocks are scheduled first (longest blocks) to minimize tail.
// winner[] must be pre-set to -1 (hipMemsetAsync 0xFF) before this kernel.
// ---------------------------------------------------------------------------
__global__ void __launch_bounds__(BLOCK) bbp_fused(
    const float* __restrict__ anchors,            // [A,4] cbox (cx,cy,w,h)
    const float* __restrict__ bboxes,             // [B,N,4] bbox
    float* __restrict__ max_iou_anchor,           // [B,A]
    int* __restrict__ box_indice,                 // [B,A]
    int* __restrict__ winner,                     // [B,A], pre-init -1
    unsigned long long* __restrict__ packed,      // [B,N]
    int A, int NA, int NBB) {
    const int bid = blockIdx.x;
    const int tid = threadIdx.x;

    if (bid < NBB) {
        // ================= pass B: per-box max/argmax over anchors ==========
        const int b = bid / NGRP;
        const int ng = bid - b * NGRP;
        const int n0 = ng * GB;
        const float* bb = bboxes + ((size_t)b * NN + n0) * 4;

        float bx1[GB], by1[GB], bx2[GB], by2[GB], sa[GB];
        #pragma unroll
        for (int g = 0; g < GB; ++g) {
            float4 v = *(const float4*)(bb + 4 * g);     // uniform -> s_load
            bx1[g] = v.x; by1[g] = v.y; bx2[g] = v.z; by2[g] = v.w;
            sa[g] = (v.z - v.x) * (v.w - v.y);
        }
        float bm[GB];
        int bxi[GB];
        #pragma unroll
        for (int g = 0; g < GB; ++g) { bm[g] = 0.0f; bxi[g] = tid; }

        const int iters = A >> 8;                        // A / 256
        #pragma unroll 4
        for (int j = 0; j < iters; ++j) {
            const int a = j * BLOCK + tid;
            const float4 ac = *(const float4*)(anchors + (size_t)a * 4); // coalesced x4
            const float ax1 = fmaf(ac.z, -0.5f, ac.x);
            const float ay1 = fmaf(ac.w, -0.5f, ac.y);
            const float ax2 = fmaf(ac.z, 0.5f, ac.x);
            const float ay2 = fmaf(ac.w, 0.5f, ac.y);
            const float area_a = ac.z * ac.w;
            #pragma unroll
            for (int g = 0; g < GB; ++g) {
                float lx = fmaxf(ax1, bx1[g]), ly = fmaxf(ay1, by1[g]);
                float rx = fminf(ax2, bx2[g]), ry = fminf(ay2, by2[g]);
                float w = fmaxf(rx - lx, 0.0f), h = fmaxf(ry - ly, 0.0f);
                float inter = w * h;
                float iou = inter * fast_rcp(area_a + sa[g] - inter);
                if (iou > bm[g]) { bm[g] = iou; bxi[g] = a; }  // strict >: smallest a
            }
        }

        // once-per-block combine: wave shfl reduce -> LDS -> 4 final writes
        __shared__ unsigned long long sred[GB][BLOCK / 64];
        #pragma unroll
        for (int g = 0; g < GB; ++g) {
            unsigned long long pk =
                ((unsigned long long)__float_as_uint(bm[g]) << 32)
                | (unsigned long long)(0xFFFFFFFFu - (unsigned)bxi[g]);
            #pragma unroll
            for (int off = 32; off > 0; off >>= 1) {
                unsigned long long o = __shfl_down(pk, off, 64);
                if (o > pk) pk = o;
            }
            if ((tid & 63) == 0) sred[g][tid >> 6] = pk;
        }
        __syncthreads();
        if (tid < GB) {
            unsigned long long m = sred[tid][0];
            #pragma unroll
            for (int j = 1; j < BLOCK / 64; ++j) {
                unsigned long long o = sred[tid][j];
                if (o > m) m = o;
            }
            const int n = n0 + tid;
            packed[(size_t)b * NN + n] = m;              // sole writer, plain store
            // fused scatter: segment_max(tgt_ids, anchor_indice)
            unsigned an = 0xFFFFFFFFu - (unsigned)(m & 0xFFFFFFFFull);
            atomicMax(&winner[(size_t)b * A + an], n);
        }
    } else {
        // ================= pass A: per-anchor max/argmax over boxes =========
        const int ab = bid - NBB;
        const int b = ab / NA;
        const int a = (ab - b * NA) * BLOCK + tid;

        const float4 ac = *(const float4*)(anchors + (size_t)a * 4);
        const float ax1 = fmaf(ac.z, -0.5f, ac.x);
        const float ay1 = fmaf(ac.w, -0.5f, ac.y);
        const float ax2 = fmaf(ac.z, 0.5f, ac.x);
        const float ay2 = fmaf(ac.w, 0.5f, ac.y);
        const float area_a = ac.z * ac.w;

        const float* bbase = bboxes + (size_t)b * NN * 4;   // wave-uniform

        float best = -1.0f;
        int bi = 0;
        #pragma unroll 10
        for (int n = 0; n < NN; ++n) {
            const float4 v = *(const float4*)(bbase + 4 * n);  // uniform -> s_load
            const float sa = (v.z - v.x) * (v.w - v.y);
            float lx = fmaxf(ax1, v.x), ly = fmaxf(ay1, v.y);
            float rx = fminf(ax2, v.z), ry = fminf(ay2, v.w);
            float w = fmaxf(rx - lx, 0.0f), h = fmaxf(ry - ly, 0.0f);
            float inter = w * h;
            float iou = inter * fast_rcp(area_a + sa - inter);
            if (iou > best) { best = iou; bi = n; }   // strict >: first box
        }
        const size_t idx = (size_t)b * A + a;
        max_iou_anchor[idx] = best;
        box_indice[idx] = bi;
    }
}

// ---------------------------------------------------------------------------
// Finalize: apply override, score, one-hot conf, delta encoding.
// ---------------------------------------------------------------------------
__global__ void __launch_bounds__(BLOCK) bbp_finalize(
    const float* __restrict__ anchors, const float* __restrict__ bboxes,
    const int* __restrict__ labels, const float* __restrict__ mean4,
    const float* __restrict__ std4, const float* __restrict__ thr_p,
    const float* __restrict__ max_iou_anchor, const int* __restrict__ box_indice,
    const int* __restrict__ winner, const unsigned long long* __restrict__ packed,
    float* __restrict__ out_conf, float* __restrict__ out_deltas,
    int A, int N, int C) {
    const int b = blockIdx.y;
    const int a = blockIdx.x * BLOCK + threadIdx.x;
    if (a >= A) return;
    const float thr = thr_p[0];
    const size_t idx = (size_t)b * A + a;

    int w = winner[idx];
    bool valid = (w >= 0);
    int bi = valid ? w : box_indice[idx];      // final box index (winner==w<=N-1)
    unsigned long long pk = packed[(size_t)b * N + bi];
    float mb = __uint_as_float((unsigned)(pk >> 32));   // max_iou_of_bbox[bi]
    float miou = valid ? mb : max_iou_anchor[idx];
    float denom = fmaxf(mb, thr);
    if (miou < thr * 0.5f) miou = 0.0f;
    float score = miou * fast_rcp(denom);
    int lab = labels[(size_t)b * N + bi];
    if (lab <= 0) { score = 0.0f; lab = 0; }

    for (int c = 0; c < C; ++c)
        out_conf[idx * C + c] = (lab == c + 1) ? score : 0.0f;

    float4 bb = *(const float4*)(bboxes + ((size_t)b * N + bi) * 4);
    float4 ac = *(const float4*)(anchors + (size_t)a * 4);
    float cx = (bb.x + bb.z) * 0.5f;
    float cy = (bb.y + bb.w) * 0.5f;
    float bw = bb.z - bb.x;
    float bh = bb.w - bb.y;
    const float rz = fast_rcp(ac.z), rw = fast_rcp(ac.w);
    float4 d;
    d.x = ((cx - ac.x) * rz - mean4[0]) * fast_rcp(std4[0]);
    d.y = ((cy - ac.y) * rw - mean4[1]) * fast_rcp(std4[1]);
    d.z = (__logf(bw * rz) - mean4[2]) * fast_rcp(std4[2]);
    d.w = (__logf(bh * rw) - mean4[3]) * fast_rcp(std4[3]);
    *(float4*)(out_deltas + idx * 4) = d;
}

// ---------------------------------------------------------------------------
extern "C" void kernel_launch(void* const* d_in, const int* in_sizes, int n_in,
                              void* d_out, int out_size, void* d_ws, size_t ws_size,
                              hipStream_t stream) {
    const float* anchors = (const float*)d_in[0];
    const int* labels = (const int*)d_in[1];
    const float* bboxes = (const float*)d_in[2];
    const float* mean4 = (const float*)d_in[3];
    const float* std4 = (const float*)d_in[4];
    const float* thr_p = (const float*)d_in[5];

    const int A = in_sizes[0] / 4;        // 65536
    const int BN = in_sizes[1];           // 800
    const int N = NN;                     // 100
    const int B = BN / N;                 // 8
    const int C = out_size / (B * A) - 4; // 1
    const int NA = A / BLOCK;             // 256 pass-A blocks per image
    const int NBB = B * NGRP;             // 200 pass-B blocks

    char* ws = (char*)d_ws;
    unsigned long long* packed = (unsigned long long*)ws;                      // [B*N]
    size_t off = ((size_t)B * N * sizeof(unsigned long long) + 255) & ~(size_t)255;
    float* max_iou_anchor = (float*)(ws + off); off += (size_t)B * A * sizeof(float);
    off = (off + 255) & ~(size_t)255;
    int* box_indice = (int*)(ws + off); off += (size_t)B * A * sizeof(int);
    off = (off + 255) & ~(size_t)255;
    int* winner = (int*)(ws + off);

    float* out_conf = (float*)d_out;
    float* out_deltas = out_conf + (size_t)B * A * C;

    // winner = -1 everywhere (0xFF bytes), graph-capturable
    hipMemsetAsync(winner, 0xFF, (size_t)B * A * sizeof(int), stream);

    bbp_fused<<<dim3(NBB + B * NA), dim3(BLOCK), 0, stream>>>(
        anchors, bboxes, max_iou_anchor, box_indice, winner, packed, A, NA, NBB);

    dim3 grid(NA, B);
    bbp_finalize<<<grid, dim3(BLOCK), 0, stream>>>(anchors, bboxes, labels, mean4, std4,
                                                   thr_p, max_iou_anchor, box_indice,
                                                   winner, packed, out_conf, out_deltas,
                                                   A, N, C);
}

// Round 7
// 131.129 us; speedup vs baseline: 1.2475x; 1.2475x over previous
//
#include <hip/hip_runtime.h>
#include <math.h>

#define BLOCK 256
#define NN 100
#define GB 4             // boxes per pass-B block
#define NGRP (NN / GB)   // 25 box-groups per image
#define SPLIT 8          // anchor-dimension splits for pass B
#define FLAG 0x40000000  // "override winner" marker in box_indice

__device__ __forceinline__ float fast_rcp(float x) { return __builtin_amdgcn_rcpf(x); }

// ---------------------------------------------------------------------------
// Fused match kernel.
//  blocks [0, NBB)          : pass B — per-box partial column max over an
//                             anchor slab (A/SPLIT anchors), plain store of
//                             packed partial (sole writer, no atomics).
//  blocks [NBB, NBB + B*NA) : pass A — per-anchor row max over 100 boxes.
// ---------------------------------------------------------------------------
__global__ void __launch_bounds__(BLOCK) bbp_fused(
    const float* __restrict__ anchors,            // [A,4] cbox (cx,cy,w,h)
    const float* __restrict__ bboxes,             // [B,N,4] bbox
    float* __restrict__ max_iou_anchor,           // [B,A]
    int* __restrict__ box_indice,                 // [B,A]
    unsigned long long* __restrict__ packed_part, // [B,N,SPLIT]
    int A, int NA, int NBB) {
    const int bid = blockIdx.x;
    const int tid = threadIdx.x;

    if (bid < NBB) {
        // ========== pass B: per-box partial max over one anchor slab ========
        const int b = bid / (NGRP * SPLIT);
        const int rem = bid - b * (NGRP * SPLIT);
        const int ng = rem / SPLIT;
        const int sp = rem - ng * SPLIT;
        const int n0 = ng * GB;
        const int SA = A / SPLIT;                 // 8192 anchors per slab
        const int abase = sp * SA;
        const float* bb = bboxes + ((size_t)b * NN + n0) * 4;

        float bx1[GB], by1[GB], bx2[GB], by2[GB], sa[GB];
        #pragma unroll
        for (int g = 0; g < GB; ++g) {
            float4 v = *(const float4*)(bb + 4 * g);     // uniform -> s_load
            bx1[g] = v.x; by1[g] = v.y; bx2[g] = v.z; by2[g] = v.w;
            sa[g] = (v.z - v.x) * (v.w - v.y);
        }
        float bm[GB];
        int bxi[GB];
        #pragma unroll
        for (int g = 0; g < GB; ++g) { bm[g] = 0.0f; bxi[g] = abase + tid; }

        const int iters = SA >> 8;                       // 32
        #pragma unroll 4
        for (int j = 0; j < iters; ++j) {
            const int a = abase + j * BLOCK + tid;
            const float4 ac = *(const float4*)(anchors + (size_t)a * 4); // coalesced
            const float ax1 = fmaf(ac.z, -0.5f, ac.x);
            const float ay1 = fmaf(ac.w, -0.5f, ac.y);
            const float ax2 = fmaf(ac.z, 0.5f, ac.x);
            const float ay2 = fmaf(ac.w, 0.5f, ac.y);
            const float area_a = ac.z * ac.w;
            #pragma unroll
            for (int g = 0; g < GB; ++g) {
                float lx = fmaxf(ax1, bx1[g]), ly = fmaxf(ay1, by1[g]);
                float rx = fminf(ax2, bx2[g]), ry = fminf(ay2, by2[g]);
                float w = fmaxf(rx - lx, 0.0f), h = fmaxf(ry - ly, 0.0f);
                float inter = w * h;
                float iou = inter * fast_rcp(area_a + sa[g] - inter);
                if (iou > bm[g]) { bm[g] = iou; bxi[g] = a; }  // strict >: smallest a
            }
        }

        // once-per-block combine: shfl-u64 wave reduce -> LDS -> plain store
        __shared__ unsigned long long sred[GB][BLOCK / 64];
        #pragma unroll
        for (int g = 0; g < GB; ++g) {
            unsigned long long pk =
                ((unsigned long long)__float_as_uint(bm[g]) << 32)
                | (unsigned long long)(0xFFFFFFFFu - (unsigned)bxi[g]);
            #pragma unroll
            for (int off = 32; off > 0; off >>= 1) {
                unsigned long long o = __shfl_down(pk, off, 64);
                if (o > pk) pk = o;
            }
            if ((tid & 63) == 0) sred[g][tid >> 6] = pk;
        }
        __syncthreads();
        if (tid < GB) {
            unsigned long long m = sred[tid][0];
            #pragma unroll
            for (int j = 1; j < BLOCK / 64; ++j) {
                unsigned long long o = sred[tid][j];
                if (o > m) m = o;
            }
            packed_part[(((size_t)b * NN + n0 + tid) * SPLIT) + sp] = m;
        }
    } else {
        // ========== pass A: per-anchor max/argmax over boxes ================
        const int ab = bid - NBB;
        const int b = ab / NA;
        const int a = (ab - b * NA) * BLOCK + tid;

        const float4 ac = *(const float4*)(anchors + (size_t)a * 4);
        const float ax1 = fmaf(ac.z, -0.5f, ac.x);
        const float ay1 = fmaf(ac.w, -0.5f, ac.y);
        const float ax2 = fmaf(ac.z, 0.5f, ac.x);
        const float ay2 = fmaf(ac.w, 0.5f, ac.y);
        const float area_a = ac.z * ac.w;

        const float* bbase = bboxes + (size_t)b * NN * 4;   // wave-uniform

        float best = -1.0f;
        int bi = 0;
        #pragma unroll 10
        for (int n = 0; n < NN; ++n) {
            const float4 v = *(const float4*)(bbase + 4 * n);  // uniform -> s_load
            const float sa = (v.z - v.x) * (v.w - v.y);
            float lx = fmaxf(ax1, v.x), ly = fmaxf(ay1, v.y);
            float rx = fminf(ax2, v.z), ry = fminf(ay2, v.w);
            float w = fmaxf(rx - lx, 0.0f), h = fmaxf(ry - ly, 0.0f);
            float inter = w * h;
            float iou = inter * fast_rcp(area_a + sa - inter);
            if (iou > best) { best = iou; bi = n; }   // strict >: first box
        }
        const size_t idx = (size_t)b * A + a;
        max_iou_anchor[idx] = best;
        box_indice[idx] = bi;
    }
}

// ---------------------------------------------------------------------------
// Combine: reduce SPLIT partials -> packed; fused override scatter into
// box_indice via atomicMax(n | FLAG). Flagged values (>= FLAG) always beat
// pass-A values (< N); max over flagged n == segment_max semantics.
// ---------------------------------------------------------------------------
__global__ void __launch_bounds__(BLOCK) bbp_combine(
    const unsigned long long* __restrict__ packed_part,  // [B,N,SPLIT]
    unsigned long long* __restrict__ packed,             // [B,N]
    int* __restrict__ box_indice,                        // [B,A]
    int A, int total) {
    int i = blockIdx.x * BLOCK + threadIdx.x;
    if (i >= total) return;
    unsigned long long m = packed_part[(size_t)i * SPLIT];
    #pragma unroll
    for (int j = 1; j < SPLIT; ++j) {
        unsigned long long o = packed_part[(size_t)i * SPLIT + j];
        if (o > m) m = o;
    }
    packed[i] = m;
    int b = i / NN;
    int n = i - b * NN;
    unsigned an = 0xFFFFFFFFu - (unsigned)(m & 0xFFFFFFFFull);
    atomicMax(&box_indice[(size_t)b * A + an], n | FLAG);
}

// ---------------------------------------------------------------------------
// Finalize: decode override flag, score, one-hot conf, delta encoding.
// ---------------------------------------------------------------------------
__global__ void __launch_bounds__(BLOCK) bbp_finalize(
    const float* __restrict__ anchors, const float* __restrict__ bboxes,
    const int* __restrict__ labels, const float* __restrict__ mean4,
    const float* __restrict__ std4, const float* __restrict__ thr_p,
    const float* __restrict__ max_iou_anchor, const int* __restrict__ box_indice,
    const unsigned long long* __restrict__ packed,
    float* __restrict__ out_conf, float* __restrict__ out_deltas,
    int A, int N, int C) {
    const int b = blockIdx.y;
    const int a = blockIdx.x * BLOCK + threadIdx.x;
    if (a >= A) return;
    const float thr = thr_p[0];
    const size_t idx = (size_t)b * A + a;

    int w = box_indice[idx];
    bool valid = (w >= FLAG);
    int bi = valid ? (w & (FLAG - 1)) : w;
    unsigned long long pk = packed[(size_t)b * N + bi];
    float mb = __uint_as_float((unsigned)(pk >> 32));   // max_iou_of_bbox[bi]
    float miou = valid ? mb : max_iou_anchor[idx];
    float denom = fmaxf(mb, thr);
    if (miou < thr * 0.5f) miou = 0.0f;
    float score = miou * fast_rcp(denom);
    int lab = labels[(size_t)b * N + bi];
    if (lab <= 0) { score = 0.0f; lab = 0; }

    for (int c = 0; c < C; ++c)
        out_conf[idx * C + c] = (lab == c + 1) ? score : 0.0f;

    float4 bb = *(const float4*)(bboxes + ((size_t)b * N + bi) * 4);
    float4 ac = *(const float4*)(anchors + (size_t)a * 4);
    float cx = (bb.x + bb.z) * 0.5f;
    float cy = (bb.y + bb.w) * 0.5f;
    float bw = bb.z - bb.x;
    float bh = bb.w - bb.y;
    const float rz = fast_rcp(ac.z), rw = fast_rcp(ac.w);
    float4 d;
    d.x = ((cx - ac.x) * rz - mean4[0]) * fast_rcp(std4[0]);
    d.y = ((cy - ac.y) * rw - mean4[1]) * fast_rcp(std4[1]);
    d.z = (__logf(bw * rz) - mean4[2]) * fast_rcp(std4[2]);
    d.w = (__logf(bh * rw) - mean4[3]) * fast_rcp(std4[3]);
    *(float4*)(out_deltas + idx * 4) = d;
}

// ---------------------------------------------------------------------------
extern "C" void kernel_launch(void* const* d_in, const int* in_sizes, int n_in,
                              void* d_out, int out_size, void* d_ws, size_t ws_size,
                              hipStream_t stream) {
    const float* anchors = (const float*)d_in[0];
    const int* labels = (const int*)d_in[1];
    const float* bboxes = (const float*)d_in[2];
    const float* mean4 = (const float*)d_in[3];
    const float* std4 = (const float*)d_in[4];
    const float* thr_p = (const float*)d_in[5];

    const int A = in_sizes[0] / 4;        // 65536
    const int BN = in_sizes[1];           // 800
    const int N = NN;                     // 100
    const int B = BN / N;                 // 8
    const int C = out_size / (B * A) - 4; // 1
    const int NA = A / BLOCK;             // 256 pass-A block-groups per image
    const int NBB = B * NGRP * SPLIT;     // 1600 pass-B blocks

    char* ws = (char*)d_ws;
    unsigned long long* packed_part = (unsigned long long*)ws;                 // [B*N*SPLIT]
    size_t off = ((size_t)B * N * SPLIT * sizeof(unsigned long long) + 255) & ~(size_t)255;
    unsigned long long* packed = (unsigned long long*)(ws + off);
    off += ((size_t)B * N * sizeof(unsigned long long) + 255) & ~(size_t)255;
    float* max_iou_anchor = (float*)(ws + off); off += (size_t)B * A * sizeof(float);
    off = (off + 255) & ~(size_t)255;
    int* box_indice = (int*)(ws + off);

    float* out_conf = (float*)d_out;
    float* out_deltas = out_conf + (size_t)B * A * C;

    bbp_fused<<<dim3(NBB + B * NA), dim3(BLOCK), 0, stream>>>(
        anchors, bboxes, max_iou_anchor, box_indice, packed_part, A, NA, NBB);

    bbp_combine<<<dim3((B * N + BLOCK - 1) / BLOCK), dim3(BLOCK), 0, stream>>>(
        packed_part, packed, box_indice, A, B * N);

    dim3 grid(NA, B);
    bbp_finalize<<<grid, dim3(BLOCK), 0, stream>>>(anchors, bboxes, labels, mean4, std4,
                                                   thr_p, max_iou_anchor, box_indice,
                                                   packed, out_conf, out_deltas,
                                                   A, N, C);
}

// Round 8
// 125.305 us; speedup vs baseline: 1.3054x; 1.0465x over previous
//
#include <hip/hip_runtime.h>
#include <math.h>

#define BLOCK 256
#define NN 100
#define GB 4             // boxes per pass-B block
#define NGRP (NN / GB)   // 25 box-groups per image
#define SPLIT 16         // anchor-dimension splits for pass B
#define FLAG 0x40000000  // "override winner" marker in box_indice

__device__ __forceinline__ float fast_rcp(float x) { return __builtin_amdgcn_rcpf(x); }

// ---------------------------------------------------------------------------
// Fused match kernel.
//  blocks [0, NAB)          : pass A — per-anchor row max over 100 boxes
//                             (longest blocks, dispatched first).
//  blocks [NAB, NAB + NBB)  : pass B — per-box partial column max over a
//                             4096-anchor slab, plain store (sole writer).
// ---------------------------------------------------------------------------
__global__ void __launch_bounds__(BLOCK) bbp_fused(
    const float* __restrict__ anchors,            // [A,4] cbox (cx,cy,w,h)
    const float* __restrict__ bboxes,             // [B,N,4] bbox
    float* __restrict__ max_iou_anchor,           // [B,A]
    int* __restrict__ box_indice,                 // [B,A]
    unsigned long long* __restrict__ packed_part, // [B,N,SPLIT]
    int A, int NA, int NAB) {
    const int bid = blockIdx.x;
    const int tid = threadIdx.x;

    if (bid < NAB) {
        // ========== pass A: per-anchor max/argmax over boxes ================
        const int b = bid / NA;
        const int a = (bid - b * NA) * BLOCK + tid;

        __shared__ float sarea[NN];
        if (tid < NN) {
            float4 v = *(const float4*)(bboxes + ((size_t)b * NN + tid) * 4);
            sarea[tid] = (v.z - v.x) * (v.w - v.y);
        }
        __syncthreads();

        const float4 ac = *(const float4*)(anchors + (size_t)a * 4);
        const float ax1 = fmaf(ac.z, -0.5f, ac.x);
        const float ay1 = fmaf(ac.w, -0.5f, ac.y);
        const float ax2 = fmaf(ac.z, 0.5f, ac.x);
        const float ay2 = fmaf(ac.w, 0.5f, ac.y);
        const float area_a = ac.z * ac.w;

        const float* bbase = bboxes + (size_t)b * NN * 4;   // wave-uniform

        float best = -1.0f;
        int bi = 0;
        #pragma unroll 10
        for (int n = 0; n < NN; ++n) {
            const float4 v = *(const float4*)(bbase + 4 * n);  // uniform -> s_load
            const float sa = sarea[n];                         // LDS broadcast
            float lx = fmaxf(ax1, v.x), ly = fmaxf(ay1, v.y);
            float rx = fminf(ax2, v.z), ry = fminf(ay2, v.w);
            float w = fmaxf(rx - lx, 0.0f), h = fmaxf(ry - ly, 0.0f);
            float inter = w * h;
            float iou = inter * fast_rcp(area_a + sa - inter);
            if (iou > best) { best = iou; bi = n; }   // strict >: first box
        }
        const size_t idx = (size_t)b * A + a;
        max_iou_anchor[idx] = best;
        box_indice[idx] = bi;
    } else {
        // ========== pass B: per-box partial max over one anchor slab ========
        const int pb = bid - NAB;
        const int b = pb / (NGRP * SPLIT);
        const int rem = pb - b * (NGRP * SPLIT);
        const int ng = rem / SPLIT;
        const int sp = rem - ng * SPLIT;
        const int n0 = ng * GB;
        const int SA = A / SPLIT;                 // 4096 anchors per slab
        const int abase = sp * SA;
        const float* bb = bboxes + ((size_t)b * NN + n0) * 4;

        float bx1[GB], by1[GB], bx2[GB], by2[GB], sa[GB];
        #pragma unroll
        for (int g = 0; g < GB; ++g) {
            float4 v = *(const float4*)(bb + 4 * g);     // uniform -> s_load
            bx1[g] = v.x; by1[g] = v.y; bx2[g] = v.z; by2[g] = v.w;
            sa[g] = (v.z - v.x) * (v.w - v.y);
        }
        float bm[GB];
        int bxi[GB];
        #pragma unroll
        for (int g = 0; g < GB; ++g) { bm[g] = 0.0f; bxi[g] = abase + tid; }

        const int iters = SA >> 8;                       // 16
        #pragma unroll 4
        for (int j = 0; j < iters; ++j) {
            const int a = abase + j * BLOCK + tid;
            const float4 ac = *(const float4*)(anchors + (size_t)a * 4); // coalesced
            const float ax1 = fmaf(ac.z, -0.5f, ac.x);
            const float ay1 = fmaf(ac.w, -0.5f, ac.y);
            const float ax2 = fmaf(ac.z, 0.5f, ac.x);
            const float ay2 = fmaf(ac.w, 0.5f, ac.y);
            const float area_a = ac.z * ac.w;
            #pragma unroll
            for (int g = 0; g < GB; ++g) {
                float lx = fmaxf(ax1, bx1[g]), ly = fmaxf(ay1, by1[g]);
                float rx = fminf(ax2, bx2[g]), ry = fminf(ay2, by2[g]);
                float w = fmaxf(rx - lx, 0.0f), h = fmaxf(ry - ly, 0.0f);
                float inter = w * h;
                float iou = inter * fast_rcp(area_a + sa[g] - inter);
                if (iou > bm[g]) { bm[g] = iou; bxi[g] = a; }  // strict >: smallest a
            }
        }

        // once-per-block combine: shfl-u64 wave reduce -> LDS -> plain store
        __shared__ unsigned long long sred[GB][BLOCK / 64];
        #pragma unroll
        for (int g = 0; g < GB; ++g) {
            unsigned long long pk =
                ((unsigned long long)__float_as_uint(bm[g]) << 32)
                | (unsigned long long)(0xFFFFFFFFu - (unsigned)bxi[g]);
            #pragma unroll
            for (int off = 32; off > 0; off >>= 1) {
                unsigned long long o = __shfl_down(pk, off, 64);
                if (o > pk) pk = o;
            }
            if ((tid & 63) == 0) sred[g][tid >> 6] = pk;
        }
        __syncthreads();
        if (tid < GB) {
            unsigned long long m = sred[tid][0];
            #pragma unroll
            for (int j = 1; j < BLOCK / 64; ++j) {
                unsigned long long o = sred[tid][j];
                if (o > m) m = o;
            }
            packed_part[(((size_t)b * NN + n0 + tid) * SPLIT) + sp] = m;
        }
    }
}

// ---------------------------------------------------------------------------
// Combine: reduce SPLIT partials -> packed; fused override scatter into
// box_indice via atomicMax(n | FLAG). Flagged values (>= FLAG) always beat
// pass-A values (< N); max over flagged n == segment_max semantics.
// ---------------------------------------------------------------------------
__global__ void __launch_bounds__(BLOCK) bbp_combine(
    const unsigned long long* __restrict__ packed_part,  // [B,N,SPLIT]
    unsigned long long* __restrict__ packed,             // [B,N]
    int* __restrict__ box_indice,                        // [B,A]
    int A, int total) {
    int i = blockIdx.x * BLOCK + threadIdx.x;
    if (i >= total) return;
    unsigned long long m = packed_part[(size_t)i * SPLIT];
    #pragma unroll
    for (int j = 1; j < SPLIT; ++j) {
        unsigned long long o = packed_part[(size_t)i * SPLIT + j];
        if (o > m) m = o;
    }
    packed[i] = m;
    int b = i / NN;
    int n = i - b * NN;
    unsigned an = 0xFFFFFFFFu - (unsigned)(m & 0xFFFFFFFFull);
    atomicMax(&box_indice[(size_t)b * A + an], n | FLAG);
}

// ---------------------------------------------------------------------------
// Finalize: decode override flag, score, one-hot conf, delta encoding.
// ---------------------------------------------------------------------------
__global__ void __launch_bounds__(BLOCK) bbp_finalize(
    const float* __restrict__ anchors, const float* __restrict__ bboxes,
    const int* __restrict__ labels, const float* __restrict__ mean4,
    const float* __restrict__ std4, const float* __restrict__ thr_p,
    const float* __restrict__ max_iou_anchor, const int* __restrict__ box_indice,
    const unsigned long long* __restrict__ packed,
    float* __restrict__ out_conf, float* __restrict__ out_deltas,
    int A, int N, int C) {
    const int b = blockIdx.y;
    const int a = blockIdx.x * BLOCK + threadIdx.x;
    if (a >= A) return;
    const float thr = thr_p[0];
    const size_t idx = (size_t)b * A + a;

    int w = box_indice[idx];
    bool valid = (w >= FLAG);
    int bi = valid ? (w & (FLAG - 1)) : w;
    unsigned long long pk = packed[(size_t)b * N + bi];
    float mb = __uint_as_float((unsigned)(pk >> 32));   // max_iou_of_bbox[bi]
    float miou = valid ? mb : max_iou_anchor[idx];
    float denom = fmaxf(mb, thr);
    if (miou < thr * 0.5f) miou = 0.0f;
    float score = miou * fast_rcp(denom);
    int lab = labels[(size_t)b * N + bi];
    if (lab <= 0) { score = 0.0f; lab = 0; }

    for (int c = 0; c < C; ++c)
        out_conf[idx * C + c] = (lab == c + 1) ? score : 0.0f;

    float4 bb = *(const float4*)(bboxes + ((size_t)b * N + bi) * 4);
    float4 ac = *(const float4*)(anchors + (size_t)a * 4);
    float cx = (bb.x + bb.z) * 0.5f;
    float cy = (bb.y + bb.w) * 0.5f;
    float bw = bb.z - bb.x;
    float bh = bb.w - bb.y;
    const float rz = fast_rcp(ac.z), rw = fast_rcp(ac.w);
    float4 d;
    d.x = ((cx - ac.x) * rz - mean4[0]) * fast_rcp(std4[0]);
    d.y = ((cy - ac.y) * rw - mean4[1]) * fast_rcp(std4[1]);
    d.z = (__logf(bw * rz) - mean4[2]) * fast_rcp(std4[2]);
    d.w = (__logf(bh * rw) - mean4[3]) * fast_rcp(std4[3]);
    *(float4*)(out_deltas + idx * 4) = d;
}

// ---------------------------------------------------------------------------
extern "C" void kernel_launch(void* const* d_in, const int* in_sizes, int n_in,
                              void* d_out, int out_size, void* d_ws, size_t ws_size,
                              hipStream_t stream) {
    const float* anchors = (const float*)d_in[0];
    const int* labels = (const int*)d_in[1];
    const float* bboxes = (const float*)d_in[2];
    const float* mean4 = (const float*)d_in[3];
    const float* std4 = (const float*)d_in[4];
    const float* thr_p = (const float*)d_in[5];

    const int A = in_sizes[0] / 4;        // 65536
    const int BN = in_sizes[1];           // 800
    const int N = NN;                     // 100
    const int B = BN / N;                 // 8
    const int C = out_size / (B * A) - 4; // 1
    const int NA = A / BLOCK;             // 256 pass-A block-groups per image
    const int NAB = B * NA;               // 2048 pass-A blocks
    const int NBB = B * NGRP * SPLIT;     // 3200 pass-B blocks

    char* ws = (char*)d_ws;
    unsigned long long* packed_part = (unsigned long long*)ws;                 // [B*N*SPLIT]
    size_t off = ((size_t)B * N * SPLIT * sizeof(unsigned long long) + 255) & ~(size_t)255;
    unsigned long long* packed = (unsigned long long*)(ws + off);
    off += ((size_t)B * N * sizeof(unsigned long long) + 255) & ~(size_t)255;
    float* max_iou_anchor = (float*)(ws + off); off += (size_t)B * A * sizeof(float);
    off = (off + 255) & ~(size_t)255;
    int* box_indice = (int*)(ws + off);

    float* out_conf = (float*)d_out;
    float* out_deltas = out_conf + (size_t)B * A * C;

    bbp_fused<<<dim3(NAB + NBB), dim3(BLOCK), 0, stream>>>(
        anchors, bboxes, max_iou_anchor, box_indice, packed_part, A, NA, NAB);

    bbp_combine<<<dim3((B * N + BLOCK - 1) / BLOCK), dim3(BLOCK), 0, stream>>>(
        packed_part, packed, box_indice, A, B * N);

    dim3 grid(NA, B);
    bbp_finalize<<<grid, dim3(BLOCK), 0, stream>>>(anchors, bboxes, labels, mean4, std4,
                                                   thr_p, max_iou_anchor, box_indice,
                                                   packed, out_conf, out_deltas,
                                                   A, N, C);
}